// Round 15
// baseline (915.323 us; speedup 1.0000x reference)
//
#include <hip/hip_runtime.h>
#include <cstddef>
#include <cstdint>

#define B_ 64
#define T_ 800
#define D_ 80
#define H_ 128
#define K_ 39
#define BT_ (B_ * T_)   // 51200

typedef _Float16 h2_t  __attribute__((ext_vector_type(2)));
typedef _Float16 f16x8 __attribute__((ext_vector_type(8)));
typedef float    f32x4 __attribute__((ext_vector_type(4)));

__device__ __forceinline__ float fdot2_(h2_t a, h2_t b, float c) {
#if __has_builtin(__builtin_amdgcn_fdot2)
  return __builtin_amdgcn_fdot2(a, b, c, false);
#else
  return c + (float)a.x * (float)b.x + (float)a.y * (float)b.y;
#endif
}

__device__ __forceinline__ h2_t asH2u_(uint32_t u) { return __builtin_bit_cast(h2_t, u); }

__device__ __forceinline__ float sigf_(float x)  { return 1.0f / (1.0f + __expf(-x)); }
__device__ __forceinline__ float tanhf_(float x) { return 2.0f / (1.0f + __expf(-2.0f * x)) - 1.0f; }

__device__ __forceinline__ float laneb_(float v, int lane) {
  return __builtin_bit_cast(float, __builtin_amdgcn_readlane(__builtin_bit_cast(int, v), lane));
}
__device__ __forceinline__ uint32_t lanebu_(uint32_t v, int lane) {
  return (uint32_t)__builtin_amdgcn_readlane((int)v, lane);
}

// DPP quad_perm broadcast of quad-lane q (imm = q replicated in 4 slots).
template<int IMM>
__device__ __forceinline__ float dppq_(float v) {
  return __builtin_bit_cast(float,
    __builtin_amdgcn_mov_dpp(__builtin_bit_cast(int, v), IMM, 0xF, 0xF, true));
}

// LDS-only barrier: waits LDS ops but does NOT drain vmem.
__device__ __forceinline__ void barrier_lds_() {
  asm volatile("s_waitcnt lgkmcnt(0)" ::: "memory");
  __builtin_amdgcn_s_barrier();
}

// ---------------------------------------------------------------------------
// xw via MFMA 16x16x32 f16. Output layout matches the R15 lstm thread map:
// row r = gate*128 + unit  ->  flat idx = (unit>>4)*64 + (unit&15)*4 + gate.
// In this kernel: gate = wave w, unit = nt*16 + lm  ->  idx = nt*64 + lm*4 + w.
// ---------------------------------------------------------------------------
__global__ __launch_bounds__(256, 1)
void xw_kernel(const float* __restrict__ x,
               const float* __restrict__ Wih_f, const float* __restrict__ Wih_b,
               _Float16* __restrict__ xw)
{
  const int dir = blockIdx.x & 1;
  const int mc  = blockIdx.x >> 1;           // 0..99
  const float* W = dir ? Wih_b : Wih_f;

  const int tid  = threadIdx.x;
  const int w    = tid >> 6;                 // gate block 0=i 1=f 2=g 3=o
  const int lane = tid & 63;
  const int lm   = lane & 15;
  const int quad = lane >> 4;

  f16x8 Bf[8][3];
  #pragma unroll
  for (int nt = 0; nt < 8; ++nt) {
    const int r = w * 128 + nt * 16 + lm;
    #pragma unroll
    for (int kt = 0; kt < 3; ++kt) {
      const int kb = kt * 32 + quad * 8;
      #pragma unroll
      for (int j = 0; j < 8; ++j) {
        const int k = kb + j;
        Bf[nt][kt][j] = (k < D_) ? (_Float16)W[(size_t)r * D_ + k] : (_Float16)0.0f;
      }
    }
  }

  __shared__ alignas(16) _Float16 xs[128 * 96];   // 24 KB, K padded to 96
  for (int i = tid; i < 128 * 96; i += 256) xs[i] = (_Float16)0.0f;

  for (int cc = 0; cc < 4; ++cc) {
    const int base = mc * 512 + cc * 128;
    __syncthreads();
    {
      const float4* src = (const float4*)(x + (size_t)base * D_);
      for (int i = tid; i < 128 * D_ / 4; i += 256) {
        float4 v = src[i];
        const int row = i / 20, col = (i % 20) * 4;
        h2_t p0, p1;
        p0.x = (_Float16)v.x; p0.y = (_Float16)v.y;
        p1.x = (_Float16)v.z; p1.y = (_Float16)v.w;
        uint2 pk;
        pk.x = __builtin_bit_cast(uint32_t, p0);
        pk.y = __builtin_bit_cast(uint32_t, p1);
        *(uint2*)&xs[row * 96 + col] = pk;
      }
    }
    __syncthreads();

    #pragma unroll
    for (int mt = 0; mt < 8; ++mt) {
      f16x8 Af[3];
      #pragma unroll
      for (int kt = 0; kt < 3; ++kt)
        Af[kt] = *(const f16x8*)&xs[(mt * 16 + lm) * 96 + kt * 32 + quad * 8];

      f32x4 acc[8];
      #pragma unroll
      for (int nt = 0; nt < 8; ++nt) acc[nt] = (f32x4){0.f, 0.f, 0.f, 0.f};
      #pragma unroll
      for (int kt = 0; kt < 3; ++kt)
        #pragma unroll
        for (int nt = 0; nt < 8; ++nt)
          acc[nt] = __builtin_amdgcn_mfma_f32_16x16x32_f16(Af[kt], Bf[nt][kt], acc[nt], 0, 0, 0);

      #pragma unroll
      for (int nt = 0; nt < 8; ++nt) {
        const int idx = nt * 64 + lm * 4 + w;   // R15 lstm thread layout
        #pragma unroll
        for (int rg = 0; rg < 4; ++rg) {
          const int bt = base + mt * 16 + quad * 4 + rg;
          xw[((size_t)dir * BT_ + bt) * 512 + idx] = (_Float16)acc[nt][rg];
        }
      }
    }
  }
}

// ---------------------------------------------------------------------------
// Recurrent LSTM, R=1 quad-gate. Grid 128 (one WG per (b,dir), 1 WG/CU),
// 512 threads = 8 waves = 2 waves/SIMD (the R14 structure had 1 wave/SIMD
// and ~1080 exposed stall cyc/step at VALUBusy 34%; two co-resident waves
// per SIMD hide each other's stalls without halving CU count).
// Thread (wave w, lane L): unit = w*16 + (L>>2), gate = L&3,
// owns Whh row gate*128+unit (64 h2 VGPRs). Gate exchange: 4 DPP
// quad-broadcasts (lanes 4u+0..3 hold i,f,g,o of unit) — pure VALU.
// One exp per lane via unified sig/tanh form. h broadcast via readlane.
// ---------------------------------------------------------------------------
template<int USE_XW>
__global__ __launch_bounds__(512, 2)
void lstm_kernel(const float* __restrict__ x,
                 const float* __restrict__ Wih_f, const float* __restrict__ Whh_f,
                 const float* __restrict__ bih_f, const float* __restrict__ bhh_f,
                 const float* __restrict__ Wih_b, const float* __restrict__ Whh_b,
                 const float* __restrict__ bih_b, const float* __restrict__ bhh_b,
                 const _Float16* __restrict__ xw,
                 _Float16* __restrict__ hcat)
{
  const int bb  = blockIdx.x & 63;
  const int dir = blockIdx.x >> 6;
  const float* Whh = dir ? Whh_b : Whh_f;
  const float* Wih = dir ? Wih_b : Wih_f;
  const float* bih = dir ? bih_b : bih_f;
  const float* bhh = dir ? bhh_b : bhh_f;

  const int tid  = threadIdx.x;       // 0..511
  const int w    = tid >> 6;
  const int L    = tid & 63;
  const int unit = w * 16 + (L >> 2);
  const int gate = L & 3;             // 0=i 1=f 2=g 3=o
  const int r    = gate * H_ + unit;

  h2_t wh[64];
  #pragma unroll
  for (int j = 0; j < 64; ++j) {
    float2 a = *(const float2*)(Whh + (size_t)r * H_ + 2 * j);
    wh[j].x = (_Float16)a.x; wh[j].y = (_Float16)a.y;
  }
  h2_t wx[40];
  if (!USE_XW) {
    #pragma unroll
    for (int i = 0; i < 40; ++i) {
      float2 a = *(const float2*)(Wih + (size_t)r * D_ + 2 * i);
      wx[i].x = (_Float16)a.x; wx[i].y = (_Float16)a.y;
    }
  }
  const float bias = bih[r] + bhh[r];
  // unified nonlinearity: e = exp(g*argm); rec = 1/(1+e); val = vscale*rec+voffs
  const float argm   = (gate == 2) ? -2.0f : -1.0f;
  const float vscale = (gate == 2) ?  2.0f :  1.0f;
  const float voffs  = (gate == 2) ? -1.0f :  0.0f;

  __shared__ alignas(8) _Float16 hsf[2][H_];   // double-buffered h
  __shared__ uint32_t xs2[2][64];              // fallback x staging

  if (tid < H_) hsf[0][tid] = (_Float16)0.0f;
  if (!USE_XW && tid < 64) { xs2[0][tid] = 0u; xs2[1][tid] = 0u; }
  float c = 0.0f;                              // all 4 quad lanes track c

  const _Float16* xwp = xw + ((size_t)dir * BT_ + (size_t)bb * T_) * 512;
  const float*    xb  = x + (size_t)bb * T_ * D_;
  _Float16*       hb  = hcat + (size_t)bb * T_ * (2 * H_) + dir * H_;

  _Float16 xwA = (_Float16)0.f, xwB = (_Float16)0.f;
  h2_t xpend; xpend.x = (_Float16)0.f; xpend.y = (_Float16)0.f;
  {
    const int tq0 = dir ? (T_ - 1) : 0;
    const int tq1 = dir ? (T_ - 2) : 1;
    if (USE_XW) {
      xwA = xwp[(size_t)tq0 * 512 + tid];
      xwB = xwp[(size_t)tq1 * 512 + tid];
    } else if (tid < 40) {
      float2 v0 = *(const float2*)(xb + (size_t)tq0 * D_ + 2 * tid);
      h2_t p; p.x = (_Float16)v0.x; p.y = (_Float16)v0.y;
      xs2[0][tid] = __builtin_bit_cast(uint32_t, p);
      float2 v1 = *(const float2*)(xb + (size_t)tq1 * D_ + 2 * tid);
      xpend.x = (_Float16)v1.x; xpend.y = (_Float16)v1.y;
    }
  }
  __syncthreads();

  auto step = [&](int tt, int par, _Float16& xwreg) {
    const int t = dir ? (T_ - 1 - tt) : tt;
    float a0 = bias, a1 = 0.f, a2 = 0.f, a3 = 0.f;
    if (USE_XW) {
      a0 += (float)xwreg;
      const int ttc = (tt + 2 < T_) ? (tt + 2) : (T_ - 1);
      const int tq2 = dir ? (T_ - 1 - ttc) : ttc;
      xwreg = xwp[(size_t)tq2 * 512 + tid];   // prefetch; consumed 2 steps later
    } else {
      if (tid < 40) {
        xs2[par ^ 1][tid] = __builtin_bit_cast(uint32_t, xpend);
        const int ttc = (tt + 2 < T_) ? (tt + 2) : (T_ - 1);
        const int tq2 = dir ? (T_ - 1 - ttc) : ttc;
        float2 v = *(const float2*)(xb + (size_t)tq2 * D_ + 2 * tid);
        xpend.x = (_Float16)v.x; xpend.y = (_Float16)v.y;
      }
      uint32_t xreg = xs2[par][L];
      #pragma unroll
      for (int j = 0; j < 40; j += 4) {
        a0 = fdot2_(wx[j],     asH2u_(lanebu_(xreg, j)),     a0);
        a1 = fdot2_(wx[j + 1], asH2u_(lanebu_(xreg, j + 1)), a1);
        a2 = fdot2_(wx[j + 2], asH2u_(lanebu_(xreg, j + 2)), a2);
        a3 = fdot2_(wx[j + 3], asH2u_(lanebu_(xreg, j + 3)), a3);
      }
    }

    const uint32_t h2reg = ((const uint32_t*)hsf[par])[L];
    #pragma unroll
    for (int j = 0; j < 64; j += 4) {
      a0 = fdot2_(wh[j],     asH2u_(lanebu_(h2reg, j)),     a0);
      a1 = fdot2_(wh[j + 1], asH2u_(lanebu_(h2reg, j + 1)), a1);
      a2 = fdot2_(wh[j + 2], asH2u_(lanebu_(h2reg, j + 2)), a2);
      a3 = fdot2_(wh[j + 3], asH2u_(lanebu_(h2reg, j + 3)), a3);
    }
    const float g = (a0 + a1) + (a2 + a3);

    // one exp per lane: sig (gates i,f,o) or tanh (gate g)
    const float e   = __expf(g * argm);
    const float rec = __builtin_amdgcn_rcpf(1.0f + e);
    const float val = fmaf(vscale, rec, voffs);

    // quad broadcasts: i,f,g,o of this unit to all 4 lanes (VALU DPP)
    const float si = dppq_<0x00>(val);
    const float sf = dppq_<0x55>(val);
    const float tg = dppq_<0xAA>(val);
    const float so = dppq_<0xFF>(val);
    c = fmaf(sf, c, si * tg);                  // redundant across quad, identical
    const float h = so * tanhf_(c);
    if (gate == 0) {
      hsf[par ^ 1][unit] = (_Float16)h;
      hb[(size_t)t * (2 * H_) + unit] = (_Float16)h;  // async, never drained
    }
    barrier_lds_();
  };

  for (int tb = 0; tb < T_; tb += 2) {
    step(tb,     0, xwA);
    step(tb + 1, 1, xwB);
  }
}

// ---------------------------------------------------------------------------
// Emissions via MFMA (unchanged).
// ---------------------------------------------------------------------------
__global__ __launch_bounds__(256, 1)
void emis_kernel(const _Float16* __restrict__ hcat,
                 const float* __restrict__ Wp, const float* __restrict__ bp,
                 float* __restrict__ em)
{
  const int tid  = threadIdx.x;
  const int w    = tid >> 6;
  const int lane = tid & 63;
  const int lm   = lane & 15;
  const int quad = lane >> 4;

  f16x8 Bf[3][8];
  float bias[3];
  #pragma unroll
  for (int nt = 0; nt < 3; ++nt) {
    const int n = nt * 16 + lm;
    const bool valid = n < K_;
    bias[nt] = valid ? bp[n] : 0.0f;
    #pragma unroll
    for (int kt = 0; kt < 8; ++kt) {
      const int kb = kt * 32 + quad * 8;
      #pragma unroll
      for (int j = 0; j < 8; ++j)
        Bf[nt][kt][j] = valid ? (_Float16)Wp[(size_t)n * 256 + kb + j] : (_Float16)0.0f;
    }
  }

  #pragma unroll
  for (int q = 0; q < 4; ++q) {
    const int mt  = blockIdx.x * 16 + w * 4 + q;
    const int bt0 = mt * 16;

    f16x8 Af[8];
    const _Float16* ab = hcat + ((size_t)bt0 + lm) * 256;
    #pragma unroll
    for (int kt = 0; kt < 8; ++kt)
      Af[kt] = *(const f16x8*)(ab + kt * 32 + quad * 8);

    f32x4 acc[3];
    #pragma unroll
    for (int nt = 0; nt < 3; ++nt) acc[nt] = (f32x4){0.f, 0.f, 0.f, 0.f};
    #pragma unroll
    for (int kt = 0; kt < 8; ++kt)
      #pragma unroll
      for (int nt = 0; nt < 3; ++nt)
        acc[nt] = __builtin_amdgcn_mfma_f32_16x16x32_f16(Af[kt], Bf[nt][kt], acc[nt], 0, 0, 0);

    #pragma unroll
    for (int nt = 0; nt < 3; ++nt) {
      const int n = nt * 16 + lm;
      if (n < K_) {
        #pragma unroll
        for (int rg = 0; rg < 4; ++rg) {
          const int row = bt0 + quad * 4 + rg;
          em[(size_t)row * K_ + n] = acc[nt][rg] + bias[nt];
        }
      }
    }
  }
}

// ---------------------------------------------------------------------------
// Fused CRF den+num (unchanged from R14).
// ---------------------------------------------------------------------------
__global__ __launch_bounds__(256)
void crf_dn_kernel(const float* __restrict__ em,
                   const int* __restrict__ labels, const int* __restrict__ lengths,
                   const float* __restrict__ start_t, const float* __restrict__ end_t,
                   const float* __restrict__ trans,
                   float* __restrict__ dn)
{
  const int b    = blockIdx.x;
  const int tid  = threadIdx.x;
  const int wv   = tid >> 6;
  const int lane = tid & 63;
  const int len  = lengths[b];
  const float* emb = em + (size_t)b * T_ * K_;

  __shared__ alignas(16) float ems[408 * K_];   // 63.6 KB
  __shared__ float s_red[4];

  float et[K_];
  float v = 0.f, off_acc = 0.f, num_acc = 0.f;

  if (wv == 0) {
    #pragma unroll
    for (int j = 0; j < K_; ++j)
      et[j] = (lane < K_) ? __expf(trans[j * K_ + lane]) : 0.0f;
    float a0 = (lane < K_) ? (start_t[lane] + emb[lane]) : -1e30f;
    float m = a0;
    #pragma unroll
    for (int off = 32; off > 0; off >>= 1) m = fmaxf(m, __shfl_xor(m, off));
    v = __expf(a0 - m);               // lanes >= 39 -> 0
    off_acc = m;
  }

  for (int p = 0; p < 2; ++p) {
    const int rbase = p * 408;
    const int rcnt  = p ? 392 : 408;
    {
      const float4* src = (const float4*)(emb + (size_t)rbase * K_);
      for (int i = tid; i < rcnt * K_ / 4; i += 256)
        ((float4*)ems)[i] = src[i];
    }
    __syncthreads();

    if (wv == 0) {
      const int ts = p ? 408 : 1;
      const int te = p ? T_ : 408;
      float emn = (lane < K_) ? ems[(ts - rbase) * K_ + lane] : 0.f;
      for (int t = ts; t < te; ++t) {
        const float emc = emn;
        const int tn = (t + 1 < te) ? (t + 1) : (te - 1);
        emn = (lane < K_) ? ems[(tn - rbase) * K_ + lane] : 0.f;   // prefetch

        const float pv = v;
        float sv[K_];
        #pragma unroll
        for (int j = 0; j < K_; ++j) sv[j] = laneb_(pv, j);
        __builtin_amdgcn_sched_barrier(0);
        float s0 = 0.f, s1 = 0.f, s2 = 0.f, s3 = 0.f;
        #pragma unroll
        for (int j = 0; j < 36; j += 4) {
          s0 = fmaf(sv[j],     et[j],     s0);
          s1 = fmaf(sv[j + 1], et[j + 1], s1);
          s2 = fmaf(sv[j + 2], et[j + 2], s2);
          s3 = fmaf(sv[j + 3], et[j + 3], s3);
        }
        s0 = fmaf(sv[36], et[36], s0);
        s1 = fmaf(sv[37], et[37], s1);
        s2 = fmaf(sv[38], et[38], s2);
        const float nv = ((s0 + s1) + (s2 + s3)) * __expf(emc);
        v = (t < len) ? nv : v;         // freeze past len (matches jnp.where)
        if ((t & 3) == 0) {             // algebra-neutral renorm, VALU only
          const float sc = laneb_(v, 0);
          v *= __builtin_amdgcn_rcpf(sc);
          off_acc += __logf(sc);
        }
      }
    } else if (p == 0) {
      const int idx = tid - 64;       // 0..191
      for (int t = 1 + idx; t < len; t += 192) {
        const int lp = labels[b * T_ + t - 1];
        const int lc = labels[b * T_ + t];
        num_acc += trans[lp * K_ + lc] + emb[(size_t)t * K_ + lc];
      }
      if (tid == 64) {
        const int l0 = labels[b * T_];
        const int ll = labels[b * T_ + len - 1];
        num_acc += start_t[l0] + emb[l0] + end_t[ll];
      }
    }
    __syncthreads();
  }

  if (wv == 0) {
    float w = (lane < K_) ? v * __expf(end_t[lane]) : 0.0f;
    #pragma unroll
    for (int off = 32; off > 0; off >>= 1) w += __shfl_xor(w, off);
    if (lane == 0) s_red[0] = off_acc + __logf(w);
  } else {
    float acc = num_acc;
    #pragma unroll
    for (int off = 32; off > 0; off >>= 1) acc += __shfl_xor(acc, off);
    if (lane == 0) s_red[wv] = acc;
  }
  __syncthreads();
  if (tid == 0) dn[b] = s_red[0] - (s_red[1] + s_red[2] + s_red[3]);
}

// out = mean(dn) over the 64 batch elements (one wave).
__global__ void finalize_kernel(const float* __restrict__ dn, float* __restrict__ out)
{
  const int tid = threadIdx.x;   // 64
  float v = dn[tid];
  #pragma unroll
  for (int off = 32; off > 0; off >>= 1) v += __shfl_down(v, off);
  if (tid == 0) out[0] = v * (1.0f / 64.0f);
}

extern "C" void kernel_launch(void* const* d_in, const int* in_sizes, int n_in,
                              void* d_out, int out_size, void* d_ws, size_t ws_size,
                              hipStream_t stream)
{
  (void)in_sizes; (void)n_in; (void)out_size;
  const float* features = (const float*)d_in[0];
  const int*   lengths  = (const int*)d_in[1];
  const int*   labels   = (const int*)d_in[2];
  const float* Wih_f = (const float*)d_in[3];
  const float* Whh_f = (const float*)d_in[4];
  const float* bih_f = (const float*)d_in[5];
  const float* bhh_f = (const float*)d_in[6];
  const float* Wih_b = (const float*)d_in[7];
  const float* Whh_b = (const float*)d_in[8];
  const float* bih_b = (const float*)d_in[9];
  const float* bhh_b = (const float*)d_in[10];
  const float* Wp      = (const float*)d_in[11];
  const float* bp      = (const float*)d_in[12];
  const float* start_t = (const float*)d_in[13];
  const float* end_t   = (const float*)d_in[14];
  const float* trans   = (const float*)d_in[15];
  float* out = (float*)d_out;

  // ws layout (bytes): hcat f16 [0, 26214400) ; em f32 [26214400, +7987200) ;
  // dn 256 B ; xw f16 [34202112, +104857600) if ws is big enough.
  char* wsc = (char*)d_ws;
  _Float16* hcatH = (_Float16*)wsc;
  float*    em    = (float*)(wsc + 26214400);
  float*    dn    = (float*)(wsc + 26214400 + 7987200);
  _Float16* xwH   = (_Float16*)(wsc + 34202112);
  const bool big  = ws_size >= (size_t)34202112 + 104857600;

  if (big) {
    hipLaunchKernelGGL(xw_kernel, dim3(200), dim3(256), 0, stream,
                       features, Wih_f, Wih_b, xwH);
    hipLaunchKernelGGL((lstm_kernel<1>), dim3(2 * B_), dim3(512), 0, stream,
                       features, Wih_f, Whh_f, bih_f, bhh_f,
                       Wih_b, Whh_b, bih_b, bhh_b, xwH, hcatH);
  } else {
    hipLaunchKernelGGL((lstm_kernel<0>), dim3(2 * B_), dim3(512), 0, stream,
                       features, Wih_f, Whh_f, bih_f, bhh_f,
                       Wih_b, Whh_b, bih_b, bhh_b, xwH, hcatH);
  }
  hipLaunchKernelGGL(emis_kernel, dim3(BT_ / 256), dim3(256), 0, stream,
                     hcatH, Wp, bp, em);
  hipLaunchKernelGGL(crf_dn_kernel, dim3(B_), dim3(256), 0, stream,
                     em, labels, lengths, start_t, end_t, trans, dn);
  hipLaunchKernelGGL(finalize_kernel, dim3(1), dim3(64), 0, stream,
                     dn, out);
}